// Round 15
// baseline (11875.340 us; speedup 1.0000x reference)
//
#include <hip/hip_runtime.h>
#include <hip/hip_bf16.h>
#include <stdint.h>

// Problem sizes (fixed)
#define NB 512     // batch
#define NS 256     // source length
#define ND 256     // hidden dim
#define NT 256     // decode steps
#define NO 3       // output dim

#define LOG2E 1.44269504088896340736f
#define C2 (2.0f*LOG2E)

typedef float f32x2 __attribute__((ext_vector_type(2)));

#if __has_builtin(__builtin_amdgcn_exp2f)
__device__ __forceinline__ float exp2_fast(float x){ return __builtin_amdgcn_exp2f(x); }
#else
__device__ __forceinline__ float exp2_fast(float x){ return exp2f(x); }
#endif
#if __has_builtin(__builtin_amdgcn_rcpf)
__device__ __forceinline__ float rcp_fast(float x){ return __builtin_amdgcn_rcpf(x); }
#else
__device__ __forceinline__ float rcp_fast(float x){ return 1.0f/x; }
#endif

__device__ __forceinline__ float tanh_f(float x){
  float e = exp2_fast(x * C2);
  return 1.0f - 2.0f*rcp_fast(e + 1.0f);
}
__device__ __forceinline__ float sigm_f(float x){
  return rcp_fast(1.0f + exp2_fast(-x*LOG2E));
}
__device__ __forceinline__ float bflo(uint32_t u){ return __uint_as_float(u<<16); }
__device__ __forceinline__ float bfhi(uint32_t u){ return __uint_as_float(u & 0xffff0000u); }
__device__ __forceinline__ uint16_t f2bf(float f){   // round-to-nearest-even bf16
  uint32_t u = __float_as_uint(f);
  return (uint16_t)((u + 0x7fffu + ((u>>16)&1u)) >> 16);
}
__device__ __forceinline__ uint32_t pack2(float a, float b){
  return (uint32_t)f2bf(a) | ((uint32_t)f2bf(b) << 16);
}

// bf16-pair dot product: c + a.lo*b.lo + a.hi*b.hi
#if __has_builtin(__builtin_amdgcn_fdot2_f32_bf16)
typedef __bf16 bfp2 __attribute__((ext_vector_type(2)));
__device__ __forceinline__ float dot2bf(uint32_t a, uint32_t b, float c){
  return __builtin_amdgcn_fdot2_f32_bf16(__builtin_bit_cast(bfp2, a),
                                         __builtin_bit_cast(bfp2, b), c, false);
}
#else
__device__ __forceinline__ float dot2bf(uint32_t a, uint32_t b, float c){
  return c + bflo(a)*bflo(b) + bfhi(a)*bfhi(b);
}
#endif

// ---- fp8 e4m3 (OCP) encode/decode ----
__device__ __forceinline__ uint8_t enc_e4m3(float x){
  uint32_t sign = (__float_as_uint(x) >> 31) << 7;
  float y = fminf(fabsf(x), 448.0f);
  uint32_t u = __float_as_uint(y);
  int e = (int)(u >> 23) - 127;
  uint32_t code;
  if (e < -6){
    code = (uint32_t)__float2int_rn(y * 512.0f);      // denormal (ulp 2^-9)
  } else {
    uint32_t r = u + 0x000FFFFFu + ((u >> 20) & 1u);  // RNE to 3 mantissa bits
    e = (int)(r >> 23) - 127;
    code = (uint32_t)((e + 7) << 3) | ((r >> 20) & 7u);
    if (code > 0x7Eu) code = 0x7Eu;                   // max finite 448
  }
  return (uint8_t)(sign | code);
}

// HI must be a compile-time constant (builtin requires literal immediate).
#if __has_builtin(__builtin_amdgcn_cvt_pk_f32_fp8)
template<bool HI>
__device__ __forceinline__ f32x2 cvtpk_fp8(uint32_t w){
  return __builtin_amdgcn_cvt_pk_f32_fp8((int)w, HI);
}
#else
__device__ __forceinline__ float dec1_e4m3(uint32_t b){
  uint32_t s = (b >> 7) << 31;
  uint32_t em = b & 0x7fu;
  float mag;
  if (em >= 8u){
    mag = __uint_as_float((((em >> 3) + 120u) << 23) | ((em & 7u) << 20));
  } else {
    mag = (float)em * 0.001953125f;  // 2^-9
  }
  return __uint_as_float(s | __float_as_uint(mag));
}
template<bool HI>
__device__ __forceinline__ f32x2 cvtpk_fp8(uint32_t w){
  uint32_t p = HI ? (w >> 16) : (w & 0xffffu);
  f32x2 r; r.x = dec1_e4m3(p & 0xffu); r.y = dec1_e4m3(p >> 8); return r;
}
#endif

// S-phase: one dword = 4 consecutive e's. Temps die immediately (low VGPR).
__device__ __forceinline__ float s_dword(uint32_t dwv, float4 qq, float4 vv, float acc){
  f32x2 lo = cvtpk_fp8<false>(dwv);
  f32x2 hi = cvtpk_fp8<true>(dwv);
  float r;
  r = rcp_fast(exp2_fast(lo.x + qq.x) + 1.f); acc = fmaf(vv.x, r, acc);
  r = rcp_fast(exp2_fast(lo.y + qq.y) + 1.f); acc = fmaf(vv.y, r, acc);
  r = rcp_fast(exp2_fast(hi.x + qq.z) + 1.f); acc = fmaf(vv.z, r, acc);
  r = rcp_fast(exp2_fast(hi.y + qq.w) + 1.f); acc = fmaf(vv.w, r, acc);
  return acc;
}
// C-phase: one dword = 4 s-values of one dim, weighted by w4.
__device__ __forceinline__ float c_dword(uint32_t dwv, float4 w4, float acc){
  f32x2 lo = cvtpk_fp8<false>(dwv);
  f32x2 hi = cvtpk_fp8<true>(dwv);
  return fmaf(w4.x,lo.x, fmaf(w4.y,lo.y, fmaf(w4.z,hi.x, fmaf(w4.w,hi.y, acc))));
}

// ---------------- prep kernels ----------------

__global__ void k_transpose(const float* __restrict__ src, float* __restrict__ dst,
                            int R, int C){
  int idx = blockIdx.x*256 + threadIdx.x;
  if (idx < R*C){
    int r = idx / C, c = idx - r*C;
    dst[c*R + r] = src[idx];
  }
}

// UKQ[b][e16][s][16] fp8 e4m3, PRE-SCALED by 2*log2e: byte j of group = e (e16*16+j)
__global__ void __launch_bounds__(256) k_uk(const float* __restrict__ e_all,
    const float* __restrict__ UaT, const float* __restrict__ bu,
    uint8_t* __restrict__ UKQ){
  __shared__ float At[ND][20];
  const int t = threadIdx.x;
  const int m0 = blockIdx.x * 16;
  const int b  = m0 >> 8;
  const int s0 = m0 & (NS-1);
  #pragma unroll
  for (int i=0;i<16;i++)
    At[t][i] = e_all[(size_t)(m0+i)*ND + t];
  __syncthreads();
  float acc[16];
  float bue = bu[t];
  #pragma unroll
  for (int i=0;i<16;i++) acc[i] = bue;
  for (int d=0; d<ND; ++d){
    float u = UaT[d*ND + t];
    const float4 a0 = *(const float4*)&At[d][0];
    const float4 a1 = *(const float4*)&At[d][4];
    const float4 a2 = *(const float4*)&At[d][8];
    const float4 a3 = *(const float4*)&At[d][12];
    acc[0]+=a0.x*u;  acc[1]+=a0.y*u;  acc[2]+=a0.z*u;  acc[3]+=a0.w*u;
    acc[4]+=a1.x*u;  acc[5]+=a1.y*u;  acc[6]+=a1.z*u;  acc[7]+=a1.w*u;
    acc[8]+=a2.x*u;  acc[9]+=a2.y*u;  acc[10]+=a2.z*u; acc[11]+=a2.w*u;
    acc[12]+=a3.x*u; acc[13]+=a3.y*u; acc[14]+=a3.z*u; acc[15]+=a3.w*u;
  }
  const int e16 = t>>4, j = t&15;
  uint8_t* base = UKQ + (((size_t)b*16 + e16)*256 + s0)*16 + j;
  #pragma unroll
  for (int i=0;i<16;i++){
    uint32_t mine = enc_e4m3(acc[i] * C2);
    uint32_t other = (uint32_t)__shfl_xor((int)mine, 1);
    if (!(t & 1))
      *(uint16_t*)(base + (size_t)i*16) = (uint16_t)(mine | (other << 8));
  }
}

// EPQ[b][s4][d] u32 = fp8 {e[4s4+0][d], e[4s4+1][d], e[4s4+2][d], e[4s4+3][d]}
__global__ void k_epq(const float* __restrict__ e_all, uint32_t* __restrict__ EPQ){
  int idx = blockIdx.x*256 + threadIdx.x;
  if (idx >= NB*64*256) return;
  int d  = idx & 255;
  int s4 = (idx >> 8) & 63;
  int b  = idx >> 14;
  const float* e = e_all + ((size_t)b*NS + 4*s4)*ND + d;
  uint32_t v = (uint32_t)enc_e4m3(e[0])
             | ((uint32_t)enc_e4m3(e[ND])   << 8)
             | ((uint32_t)enc_e4m3(e[2*ND]) << 16)
             | ((uint32_t)enc_e4m3(e[3*ND]) << 24);
  EPQ[idx] = v;
}

// WH[k2*256+d] uint4: 4 packed bf16-pair streams over h pairs {2k2,2k2+1}:
//   .x = q (Wa row d), .y = r (W_hh row d), .z = z (row 256+d), .w = n (row 512+d)
__global__ void k_wh(const float* __restrict__ Wa, const float* __restrict__ W_hh,
                     uint4* __restrict__ WH){
  int idx = blockIdx.x*256 + threadIdx.x;  // k2*256 + d
  if (idx >= 128*256) return;
  int d = idx & 255, k2 = idx >> 8;
  uint4 v;
  v.x = pack2(Wa  [(size_t)d*256       + 2*k2], Wa  [(size_t)d*256       + 2*k2+1]);
  v.y = pack2(W_hh[(size_t)d*256       + 2*k2], W_hh[(size_t)d*256       + 2*k2+1]);
  v.z = pack2(W_hh[(size_t)(256+d)*256 + 2*k2], W_hh[(size_t)(256+d)*256 + 2*k2+1]);
  v.w = pack2(W_hh[(size_t)(512+d)*256 + 2*k2], W_hh[(size_t)(512+d)*256 + 2*k2+1]);
  WH[idx] = v;
}

// WX[(k2*256+d)*3 + {0,1,2}] = {r,z,n} packed bf16-pairs over x pairs {2k2,2k2+1}
// x = [ctx(0..255); xin(256..258); pad]. k2 in [0,132); k>=259 or pad -> 0.
__global__ void k_wx(const float* __restrict__ W_ih, uint32_t* __restrict__ WX){
  int idx = blockIdx.x*256 + threadIdx.x;  // k2*256 + d
  if (idx >= 132*256) return;
  int d = idx & 255, k2 = idx >> 8;
  float r0=0,r1=0,z0=0,z1=0,n0=0,n1=0;
  int ka = 2*k2, kb = 2*k2+1;
  if (ka < 259){
    r0 = W_ih[(size_t)d*259       + ka];
    z0 = W_ih[(size_t)(256+d)*259 + ka];
    n0 = W_ih[(size_t)(512+d)*259 + ka];
  }
  if (kb < 259){
    r1 = W_ih[(size_t)d*259       + kb];
    z1 = W_ih[(size_t)(256+d)*259 + kb];
    n1 = W_ih[(size_t)(512+d)*259 + kb];
  }
  WX[(size_t)idx*3+0] = pack2(r0,r1);
  WX[(size_t)idx*3+1] = pack2(z0,z1);
  WX[(size_t)idx*3+2] = pack2(n0,n1);
}

// ---------------- persistent decode kernel ----------------
// 512 blocks x 512 threads; ONE batch per block; 2 blocks/CU (independent
// barrier domains -> one block's weight stream overlaps the other's compute).
// UK fp8 in LDS (64KB); EP fp8 in 32 resident VGPRs/thread; weights streamed.
// scr rows: 0..7 phase scratch; 8..10 = ghp(r,z,n); row2 doubles as qL (S);
// row3[0..7] doubles as softmax red.
// t: d = t&255, half = t>>8, lane = t&63, w = t>>6 (0..7).
__global__ void __launch_bounds__(512, 4) k_decode(
    const uint8_t* __restrict__ UKQ, const uint32_t* __restrict__ EPQ,
    const uint4* __restrict__ WH, const uint32_t* __restrict__ WX,
    const float* __restrict__ e_last,
    const float* __restrict__ Va, const float* __restrict__ bv,
    const float* __restrict__ b_ih, const float* __restrict__ b_hh,
    const float* __restrict__ ba, const float* __restrict__ bo,
    const float* __restrict__ Wo,
    float* __restrict__ dout, float* __restrict__ hT_out, float* __restrict__ ca)
{
  __shared__ __align__(16) uint8_t  ukl[65536];   // fp8 UK (this batch)
  __shared__ __align__(16) float    scr[11][ND];
  __shared__ __align__(16) float    va2[ND];      // 2*Va
  __shared__ __align__(16) float    wl[NS];       // softmax weights
  __shared__ float    hf[ND];
  __shared__ uint32_t xb[258];                    // [0..129]=ctx+xin pairs, [130..257]=h pairs
  __shared__ float    xin[4];

  const int t    = threadIdx.x;
  const int d    = t & 255;
  const int half = t >> 8;
  const int lane = t & 63;
  const int w    = t >> 6;      // 0..7
  const int b    = blockIdx.x;

  // ---- init ----
  if (half == 0){
    va2[d] = 2.0f*Va[d];
    hf[d]  = e_last[(size_t)b*ND + d];
    if (d < 4) xin[d] = 0.f;
  }
  const float bias_r  = b_ih[d]     + b_hh[d];
  const float bias_z  = b_ih[256+d] + b_hh[256+d];
  const float bias_ni = b_ih[512+d];
  const float bias_nh = b_hh[512+d];
  const float ba_d = ba[d];
  const float bv0  = bv[0];
  const float bo0 = bo[0], bo1 = bo[1], bo2 = bo[2];
  // UK -> LDS (64KB = 4096 uint4, 512 threads x 8)
  {
    const uint4* srcU = (const uint4*)(UKQ + (size_t)b*65536);
    uint4* dstU = (uint4*)ukl;
    #pragma unroll
    for (int i=0;i<8;i++) dstU[t + i*512] = srcU[t + i*512];
  }
  // EP -> registers (this thread's share: s4 = w*8..+8, dims lane*4..+3)
  uint4 ep[8];
  {
    const uint32_t* epb = EPQ + (size_t)b*16384;
    #pragma unroll
    for (int i=0;i<8;i++)
      ep[i] = *(const uint4*)(epb + (size_t)(w*8+i)*256 + lane*4);
  }
  __syncthreads();
  if (t < 128) xb[130+t] = pack2(hf[2*t], hf[2*t+1]);
  if (t == 128){ xb[128]=0u; xb[129]=0u; }
  float sumVaH = 0.f;   // sum of Va over this thread's e-half
  {
    #pragma unroll 8
    for (int e = half*128; e < half*128+128; ++e) sumVaH += va2[e];
    sumVaH *= 0.5f;
  }
  __syncthreads();

  float* ca_b = ca   + (size_t)b*(NT*NS);
  float* do_b = dout + (size_t)b*(NT*NO);

  #pragma unroll 1
  for (int step=0; step<NT; ++step){
    // ---- A: fused {q,r,z,n} over h; half -> 64 k2 (2-deep, low VGPR) ----
    {
      float aq=0.f, ar_=0.f, az_=0.f, an_=0.f;
      const uint4* wh = WH + (size_t)(half*64)*256 + d;
      const uint32_t* xh = &xb[130 + half*64];
      #pragma unroll 1
      for (int kk=0; kk<64; kk+=2){
        uint4 w0 = wh[(size_t)(kk+0)*256];
        uint4 w1 = wh[(size_t)(kk+1)*256];
        uint32_t x0 = xh[kk+0], x1 = xh[kk+1];
        aq =dot2bf(w0.x,x0,aq);  ar_=dot2bf(w0.y,x0,ar_);
        az_=dot2bf(w0.z,x0,az_); an_=dot2bf(w0.w,x0,an_);
        aq =dot2bf(w1.x,x1,aq);  ar_=dot2bf(w1.y,x1,ar_);
        az_=dot2bf(w1.z,x1,az_); an_=dot2bf(w1.w,x1,an_);
      }
      scr[0+half][d]=aq; scr[2+half][d]=ar_; scr[4+half][d]=az_; scr[6+half][d]=an_;
    }
    __syncthreads();
    if (half == 0){                       // column-local reduce
      float ql   = (scr[0][d]+scr[1][d] + ba_d) * C2;
      scr[8][d]  =  scr[2][d]+scr[3][d];  // ghp r
      scr[9][d]  =  scr[4][d]+scr[5][d];  // ghp z
      scr[10][d] =  scr[6][d]+scr[7][d];  // ghp n
      scr[2][d]  =  ql;                   // qL lives in row 2
    }
    __syncthreads();

    // ---- S: scores (s=d, e-half) from LDS fp8 UK ----
    {
      float acc = 0.f;
      #pragma unroll
      for (int j=0;j<8;j++){
        uint4 u = *(const uint4*)(ukl + (size_t)(((half*8+j)*256 + d) << 4));
        const float* qb = &scr[2][half*128 + j*16];
        const float* vb = &va2[half*128 + j*16];
        acc = s_dword(u.x, *(const float4*)&qb[0],  *(const float4*)&vb[0],  acc);
        acc = s_dword(u.y, *(const float4*)&qb[4],  *(const float4*)&vb[4],  acc);
        acc = s_dword(u.z, *(const float4*)&qb[8],  *(const float4*)&vb[8],  acc);
        acc = s_dword(u.w, *(const float4*)&qb[12], *(const float4*)&vb[12], acc);
      }
      scr[half][d] = sumVaH - acc;        // rows 0..1 (A partials dead)
    }
    __syncthreads();

    // ---- softmax (half==0 = waves 0..3) ----
    float p_reg = 0.f;
    if (half == 0){
      float sc = scr[0][d] + scr[1][d] + bv0;
      p_reg = exp2_fast(sc * LOG2E);
      float ssum = p_reg;
      #pragma unroll
      for (int o=32;o;o>>=1) ssum += __shfl_xor(ssum, o);
      if (lane==0) scr[3][w] = ssum;      // red in row 3 (qL row 2 is dead now)
    }
    __syncthreads();
    if (half == 0){
      float ssum = (scr[3][0]+scr[3][1]) + (scr[3][2]+scr[3][3]);
      float wgt = p_reg * rcp_fast(ssum);
      __builtin_nontemporal_store(wgt, &ca_b[(size_t)step*NS + d]);
      wl[d] = wgt;
    }
    __syncthreads();

    // ---- C: ctx from RESIDENT fp8 EP; wave w -> s4 in [w*8, +8) ----
    {
      float c0=0,c1=0,c2=0,c3=0;
      #pragma unroll
      for (int i=0;i<8;i++){
        const float4 w4 = *(const float4*)&wl[(w*8+i)*4];
        c0 = c_dword(ep[i].x, w4, c0);
        c1 = c_dword(ep[i].y, w4, c1);
        c2 = c_dword(ep[i].z, w4, c2);
        c3 = c_dword(ep[i].w, w4, c3);
      }
      *(float4*)&scr[w][lane*4] = make_float4(c0,c1,c2,c3);
    }
    __syncthreads();
    if (half == 0){
      float cx = 0.f;
      #pragma unroll
      for (int i=0;i<8;i++) cx += scr[i][d];
      float other = __shfl_xor(cx, 1);
      if (!(d&1)) xb[d>>1] = pack2(cx, other);
      if (d==128) xb[128] = pack2(xin[0], xin[1]);
      if (d==129) xb[129] = pack2(xin[2], 0.f);
    }
    __syncthreads();

    // ---- D: x-part gates {r,z,n}; half -> 66 k2 (2-deep) ----
    {
      float dr=0.f, dz=0.f, dn=0.f;
      const int k0 = half*66;
      const uint32_t* wx = WX + ((size_t)k0*256 + d)*3;
      #pragma unroll 1
      for (int kk=0; kk<66; kk+=2){
        const uint32_t* p0 = wx + (size_t)(kk+0)*768;
        const uint32_t* p1 = wx + (size_t)(kk+1)*768;
        uint32_t x0 = xb[k0+kk+0], x1 = xb[k0+kk+1];
        dr=dot2bf(p0[0],x0,dr); dz=dot2bf(p0[1],x0,dz); dn=dot2bf(p0[2],x0,dn);
        dr=dot2bf(p1[0],x1,dr); dz=dot2bf(p1[1],x1,dz); dn=dot2bf(p1[2],x1,dn);
      }
      scr[0+half][d]=dr; scr[2+half][d]=dz; scr[4+half][d]=dn;
    }
    __syncthreads();
    if (half == 0){
      float ar  = scr[0][d]+scr[1][d] + scr[8][d] + bias_r;
      float az  = scr[2][d]+scr[3][d] + scr[9][d] + bias_z;
      float ani = scr[4][d]+scr[5][d] + bias_ni;
      float anh = scr[10][d] + bias_nh;
      float rg = sigm_f(ar);
      float zg = sigm_f(az);
      float ng = tanh_f(ani + rg*anh);
      float hnew = (1.f-zg)*ng + zg*hf[d];
      hf[d] = hnew;
      float other = __shfl_xor(hnew, 1);
      if (!(d&1)) xb[130 + (d>>1)] = pack2(hnew, other);
    }
    __syncthreads();

    // ---- out projection: wave 0 (Wo straight from L2; same addr chip-wide) ----
    if (w == 0){
      float p0=0,p1=0,p2=0;
      #pragma unroll
      for (int i=0;i<4;i++){
        float hv = hf[i*64 + lane];
        p0 = fmaf(hv, Wo[      i*64+lane], p0);
        p1 = fmaf(hv, Wo[256 + i*64+lane], p1);
        p2 = fmaf(hv, Wo[512 + i*64+lane], p2);
      }
      #pragma unroll
      for (int o=32;o;o>>=1){
        p0+=__shfl_xor(p0,o); p1+=__shfl_xor(p1,o); p2+=__shfl_xor(p2,o);
      }
      if (lane==0){
        float o0=p0+bo0, o1=p1+bo1, o2=p2+bo2;
        __builtin_nontemporal_store(o0, &do_b[(size_t)step*NO+0]);
        __builtin_nontemporal_store(o1, &do_b[(size_t)step*NO+1]);
        __builtin_nontemporal_store(o2, &do_b[(size_t)step*NO+2]);
        xin[0]=o0; xin[1]=o1; xin[2]=o2;
      }
    }
    // next step's barriers order xin/hf consumers
  }

  __syncthreads();
  if (half == 0) hT_out[(size_t)b*ND + d] = hf[d];
}

// ---------------- host launch ----------------

extern "C" void kernel_launch(void* const* d_in, const int* in_sizes, int n_in,
                              void* d_out, int out_size, void* d_ws, size_t ws_size,
                              hipStream_t stream) {
  const float* e_all  = (const float*)d_in[0];
  const float* e_last = (const float*)d_in[1];
  const float* Wa     = (const float*)d_in[2];
  const float* ba     = (const float*)d_in[3];
  const float* Ua     = (const float*)d_in[4];
  const float* bu     = (const float*)d_in[5];
  const float* Va     = (const float*)d_in[6];
  const float* bv     = (const float*)d_in[7];
  const float* W_ih   = (const float*)d_in[8];
  const float* b_ih   = (const float*)d_in[9];
  const float* W_hh   = (const float*)d_in[10];
  const float* b_hh   = (const float*)d_in[11];
  const float* Wo     = (const float*)d_in[12];
  const float* bo     = (const float*)d_in[13];

  // workspace layout (~68.3 MB)
  char* ws = (char*)d_ws;
  uint8_t*  UKQ = (uint8_t*) (ws + 0ull);            // fp8 [B][16][S][16]    33554432 B
  uint32_t* EPQ = (uint32_t*)(ws + 33554432ull);     // u32 [B][64][256]      33554432 B
  uint4*    WH  = (uint4*)   (ws + 67108864ull);     // u4x [128][256]          524288 B
  uint32_t* WX  = (uint32_t*)(ws + 67633152ull);     // u32 [132][256][3]       405504 B
  float*    UaT = (float*)   (ws + 68038656ull);     // f32 [256][256]          262144 B

  float* dout = (float*)d_out;                       // [B][T][3]
  float* hT   = dout + (size_t)NB*NT*NO;             // [B][D]
  float* ca   = hT   + (size_t)NB*ND;                // [B][T*S]

  // prep
  k_transpose<<<(ND*ND+255)/256,256,0,stream>>>(Ua, UaT, ND, ND);
  k_uk<<<NB*NS/16,256,0,stream>>>(e_all, UaT, bu, UKQ);
  k_epq<<<(NB*64*256+255)/256,256,0,stream>>>(e_all, EPQ);
  k_wh<<<(128*256+255)/256,256,0,stream>>>(Wa, W_hh, WH);
  k_wx<<<(132*256+255)/256,256,0,stream>>>(W_ih, WX);

  // persistent decode: 512 blocks x 512 threads = 2 independent blocks/CU
  k_decode<<<NB,512,0,stream>>>(UKQ, EPQ, WH, WX, e_last, Va, bv,
                                b_ih, b_hh, ba, bo, Wo, dout, hT, ca);
}

// Round 17
// 9332.742 us; speedup vs baseline: 1.2724x; 1.2724x over previous
//
#include <hip/hip_runtime.h>
#include <hip/hip_bf16.h>
#include <stdint.h>

// Problem sizes (fixed)
#define NB 512     // batch
#define NS 256     // source length
#define ND 256     // hidden dim
#define NT 256     // decode steps
#define NO 3       // output dim

#define LOG2E 1.44269504088896340736f
#define C2 (2.0f*LOG2E)

typedef float f32x2 __attribute__((ext_vector_type(2)));
typedef uint32_t u32x4 __attribute__((ext_vector_type(4)));   // native vec for nt-load

#if __has_builtin(__builtin_amdgcn_exp2f)
__device__ __forceinline__ float exp2_fast(float x){ return __builtin_amdgcn_exp2f(x); }
#else
__device__ __forceinline__ float exp2_fast(float x){ return exp2f(x); }
#endif
#if __has_builtin(__builtin_amdgcn_rcpf)
__device__ __forceinline__ float rcp_fast(float x){ return __builtin_amdgcn_rcpf(x); }
#else
__device__ __forceinline__ float rcp_fast(float x){ return 1.0f/x; }
#endif

__device__ __forceinline__ float tanh_f(float x){
  float e = exp2_fast(x * C2);
  return 1.0f - 2.0f*rcp_fast(e + 1.0f);
}
__device__ __forceinline__ float sigm_f(float x){
  return rcp_fast(1.0f + exp2_fast(-x*LOG2E));
}
__device__ __forceinline__ float bflo(uint32_t u){ return __uint_as_float(u<<16); }
__device__ __forceinline__ float bfhi(uint32_t u){ return __uint_as_float(u & 0xffff0000u); }
__device__ __forceinline__ uint16_t f2bf(float f){   // round-to-nearest-even bf16
  uint32_t u = __float_as_uint(f);
  return (uint16_t)((u + 0x7fffu + ((u>>16)&1u)) >> 16);
}
__device__ __forceinline__ uint32_t pack2(float a, float b){
  return (uint32_t)f2bf(a) | ((uint32_t)f2bf(b) << 16);
}

// bf16-pair dot product: c + a.lo*b.lo + a.hi*b.hi
#if __has_builtin(__builtin_amdgcn_fdot2_f32_bf16)
typedef __bf16 bfp2 __attribute__((ext_vector_type(2)));
__device__ __forceinline__ float dot2bf(uint32_t a, uint32_t b, float c){
  return __builtin_amdgcn_fdot2_f32_bf16(__builtin_bit_cast(bfp2, a),
                                         __builtin_bit_cast(bfp2, b), c, false);
}
#else
__device__ __forceinline__ float dot2bf(uint32_t a, uint32_t b, float c){
  return c + bflo(a)*bflo(b) + bfhi(a)*bfhi(b);
}
#endif

// ---- fp8 e4m3 (OCP) encode/decode ----
__device__ __forceinline__ uint8_t enc_e4m3(float x){
  uint32_t sign = (__float_as_uint(x) >> 31) << 7;
  float y = fminf(fabsf(x), 448.0f);
  uint32_t u = __float_as_uint(y);
  int e = (int)(u >> 23) - 127;
  uint32_t code;
  if (e < -6){
    code = (uint32_t)__float2int_rn(y * 512.0f);      // denormal (ulp 2^-9)
  } else {
    uint32_t r = u + 0x000FFFFFu + ((u >> 20) & 1u);  // RNE to 3 mantissa bits
    e = (int)(r >> 23) - 127;
    code = (uint32_t)((e + 7) << 3) | ((r >> 20) & 7u);
    if (code > 0x7Eu) code = 0x7Eu;                   // max finite 448
  }
  return (uint8_t)(sign | code);
}

// HI must be a compile-time constant (builtin requires literal immediate).
#if __has_builtin(__builtin_amdgcn_cvt_pk_f32_fp8)
template<bool HI>
__device__ __forceinline__ f32x2 cvtpk_fp8(uint32_t w){
  return __builtin_amdgcn_cvt_pk_f32_fp8((int)w, HI);
}
#else
__device__ __forceinline__ float dec1_e4m3(uint32_t b){
  uint32_t s = (b >> 7) << 31;
  uint32_t em = b & 0x7fu;
  float mag;
  if (em >= 8u){
    mag = __uint_as_float((((em >> 3) + 120u) << 23) | ((em & 7u) << 20));
  } else {
    mag = (float)em * 0.001953125f;  // 2^-9
  }
  return __uint_as_float(s | __float_as_uint(mag));
}
template<bool HI>
__device__ __forceinline__ f32x2 cvtpk_fp8(uint32_t w){
  uint32_t p = HI ? (w >> 16) : (w & 0xffffu);
  f32x2 r; r.x = dec1_e4m3(p & 0xffu); r.y = dec1_e4m3(p >> 8); return r;
}
#endif

// S-phase: one dword = 4 consecutive e's. Temps die immediately (low VGPR).
__device__ __forceinline__ float s_dword(uint32_t dwv, float4 qq, float4 vv, float acc){
  f32x2 lo = cvtpk_fp8<false>(dwv);
  f32x2 hi = cvtpk_fp8<true>(dwv);
  float r;
  r = rcp_fast(exp2_fast(lo.x + qq.x) + 1.f); acc = fmaf(vv.x, r, acc);
  r = rcp_fast(exp2_fast(lo.y + qq.y) + 1.f); acc = fmaf(vv.y, r, acc);
  r = rcp_fast(exp2_fast(hi.x + qq.z) + 1.f); acc = fmaf(vv.z, r, acc);
  r = rcp_fast(exp2_fast(hi.y + qq.w) + 1.f); acc = fmaf(vv.w, r, acc);
  return acc;
}
// C-phase: one dword = 4 s-values of one dim, weighted by w4.
__device__ __forceinline__ float c_dword(uint32_t dwv, float4 w4, float acc){
  f32x2 lo = cvtpk_fp8<false>(dwv);
  f32x2 hi = cvtpk_fp8<true>(dwv);
  return fmaf(w4.x,lo.x, fmaf(w4.y,lo.y, fmaf(w4.z,hi.x, fmaf(w4.w,hi.y, acc))));
}

// ---------------- prep kernels ----------------

__global__ void k_transpose(const float* __restrict__ src, float* __restrict__ dst,
                            int R, int C){
  int idx = blockIdx.x*256 + threadIdx.x;
  if (idx < R*C){
    int r = idx / C, c = idx - r*C;
    dst[c*R + r] = src[idx];
  }
}

// UKQ[b][e16][s][16] fp8 e4m3, PRE-SCALED by 2*log2e: byte j of group = e (e16*16+j)
__global__ void __launch_bounds__(256) k_uk(const float* __restrict__ e_all,
    const float* __restrict__ UaT, const float* __restrict__ bu,
    uint8_t* __restrict__ UKQ){
  __shared__ float At[ND][20];
  const int t = threadIdx.x;
  const int m0 = blockIdx.x * 16;
  const int b  = m0 >> 8;
  const int s0 = m0 & (NS-1);
  #pragma unroll
  for (int i=0;i<16;i++)
    At[t][i] = e_all[(size_t)(m0+i)*ND + t];
  __syncthreads();
  float acc[16];
  float bue = bu[t];
  #pragma unroll
  for (int i=0;i<16;i++) acc[i] = bue;
  for (int d=0; d<ND; ++d){
    float u = UaT[d*ND + t];
    const float4 a0 = *(const float4*)&At[d][0];
    const float4 a1 = *(const float4*)&At[d][4];
    const float4 a2 = *(const float4*)&At[d][8];
    const float4 a3 = *(const float4*)&At[d][12];
    acc[0]+=a0.x*u;  acc[1]+=a0.y*u;  acc[2]+=a0.z*u;  acc[3]+=a0.w*u;
    acc[4]+=a1.x*u;  acc[5]+=a1.y*u;  acc[6]+=a1.z*u;  acc[7]+=a1.w*u;
    acc[8]+=a2.x*u;  acc[9]+=a2.y*u;  acc[10]+=a2.z*u; acc[11]+=a2.w*u;
    acc[12]+=a3.x*u; acc[13]+=a3.y*u; acc[14]+=a3.z*u; acc[15]+=a3.w*u;
  }
  const int e16 = t>>4, j = t&15;
  uint8_t* base = UKQ + (((size_t)b*16 + e16)*256 + s0)*16 + j;
  #pragma unroll
  for (int i=0;i<16;i++){
    uint32_t mine = enc_e4m3(acc[i] * C2);
    uint32_t other = (uint32_t)__shfl_xor((int)mine, 1);
    if (!(t & 1))
      *(uint16_t*)(base + (size_t)i*16) = (uint16_t)(mine | (other << 8));
  }
}

// EPQ[b][s4][d] u32 = fp8 {e[4s4+0][d], e[4s4+1][d], e[4s4+2][d], e[4s4+3][d]}
__global__ void k_epq(const float* __restrict__ e_all, uint32_t* __restrict__ EPQ){
  int idx = blockIdx.x*256 + threadIdx.x;
  if (idx >= NB*64*256) return;
  int d  = idx & 255;
  int s4 = (idx >> 8) & 63;
  int b  = idx >> 14;
  const float* e = e_all + ((size_t)b*NS + 4*s4)*ND + d;
  uint32_t v = (uint32_t)enc_e4m3(e[0])
             | ((uint32_t)enc_e4m3(e[ND])   << 8)
             | ((uint32_t)enc_e4m3(e[2*ND]) << 16)
             | ((uint32_t)enc_e4m3(e[3*ND]) << 24);
  EPQ[idx] = v;
}

// WH[k2*256+d] uint4: 4 packed bf16-pair streams over h pairs {2k2,2k2+1}:
//   .x = q (Wa row d), .y = r (W_hh row d), .z = z (row 256+d), .w = n (row 512+d)
__global__ void k_wh(const float* __restrict__ Wa, const float* __restrict__ W_hh,
                     uint4* __restrict__ WH){
  int idx = blockIdx.x*256 + threadIdx.x;  // k2*256 + d
  if (idx >= 128*256) return;
  int d = idx & 255, k2 = idx >> 8;
  uint4 v;
  v.x = pack2(Wa  [(size_t)d*256       + 2*k2], Wa  [(size_t)d*256       + 2*k2+1]);
  v.y = pack2(W_hh[(size_t)d*256       + 2*k2], W_hh[(size_t)d*256       + 2*k2+1]);
  v.z = pack2(W_hh[(size_t)(256+d)*256 + 2*k2], W_hh[(size_t)(256+d)*256 + 2*k2+1]);
  v.w = pack2(W_hh[(size_t)(512+d)*256 + 2*k2], W_hh[(size_t)(512+d)*256 + 2*k2+1]);
  WH[idx] = v;
}

// WX[(k2*256+d)*3 + {0,1,2}] = {r,z,n} packed bf16-pairs over x pairs {2k2,2k2+1}
// x = [ctx(0..255); xin(256..258); pad]. k2 in [0,132); k>=259 or pad -> 0.
__global__ void k_wx(const float* __restrict__ W_ih, uint32_t* __restrict__ WX){
  int idx = blockIdx.x*256 + threadIdx.x;  // k2*256 + d
  if (idx >= 132*256) return;
  int d = idx & 255, k2 = idx >> 8;
  float r0=0,r1=0,z0=0,z1=0,n0=0,n1=0;
  int ka = 2*k2, kb = 2*k2+1;
  if (ka < 259){
    r0 = W_ih[(size_t)d*259       + ka];
    z0 = W_ih[(size_t)(256+d)*259 + ka];
    n0 = W_ih[(size_t)(512+d)*259 + ka];
  }
  if (kb < 259){
    r1 = W_ih[(size_t)d*259       + kb];
    z1 = W_ih[(size_t)(256+d)*259 + kb];
    n1 = W_ih[(size_t)(512+d)*259 + kb];
  }
  WX[(size_t)idx*3+0] = pack2(r0,r1);
  WX[(size_t)idx*3+1] = pack2(z0,z1);
  WX[(size_t)idx*3+2] = pack2(n0,n1);
}

// ---------------- persistent decode kernel ----------------
// 256 blocks x 1024 threads; TWO batches in LOCKSTEP (weights amortized x2).
// Both batches' fp8 UK in LDS (128 KB); EP streamed with NONTEMPORAL loads
// (keeps weights L2-resident; EP comes from L3). All load batching 2-deep
// (4-deep for the short EP bursts) to stay under the 64-VGPR wall.
// t: d = t&255, q4 = t>>8, lane = t&63, w = t>>6 (0..15).
__global__ void __launch_bounds__(1024, 4) k_decode(
    const uint8_t* __restrict__ UKQ, const uint32_t* __restrict__ EPQ,
    const uint4* __restrict__ WH, const uint32_t* __restrict__ WX,
    const float* __restrict__ e_last,
    const float* __restrict__ Va, const float* __restrict__ bv,
    const float* __restrict__ b_ih, const float* __restrict__ b_hh,
    const float* __restrict__ ba, const float* __restrict__ bo,
    const float* __restrict__ Wo,
    float* __restrict__ dout, float* __restrict__ hT_out, float* __restrict__ ca)
{
  __shared__ __align__(16) uint8_t  ukl[131072];  // fp8 UK, both batches
  __shared__ __align__(16) float    scr[16][ND];  // phase scratch (2-stage acc)
  __shared__ float    ghp[2][3][ND];              // h-part gate partials (r,z,n)
  __shared__ float    hf[2][ND];
  __shared__ float    xin[2][4];
  __shared__ uint32_t xb[2][260];                 // bf16 pairs: [0..129]=ctx+x, [130..257]=h
  __shared__ __align__(16) float qL[2][ND];
  __shared__ __align__(16) float va2[ND];         // 2*Va
  __shared__ __align__(16) float wl[2][NS];       // softmax weights (f32)
  __shared__ float    red[8];

  const int t    = threadIdx.x;
  const int d    = t & 255;
  const int q4   = t >> 8;
  const int lane = t & 63;
  const int w    = t >> 6;
  const int b0   = blockIdx.x * 2;
  const int bi   = q4 >> 1;      // S-phase batch
  const int eh   = q4 & 1;       // S-phase e-half

  // ---- init ----
  if (q4 == 0) va2[d] = 2.0f*Va[d];
  if (q4 < 2){
    hf[q4][d] = e_last[(size_t)(b0+q4)*ND + d];
    if (d < 4) xin[q4][d] = 0.f;
  }
  const float bias_r  = b_ih[d]     + b_hh[d];
  const float bias_z  = b_ih[256+d] + b_hh[256+d];
  const float bias_ni = b_ih[512+d];
  const float bias_nh = b_hh[512+d];
  const float ba_d = ba[d];
  const float bv0  = bv[0];
  const float bo0 = bo[0], bo1 = bo[1], bo2 = bo[2];
  // load both batches' UK into LDS
  {
    const uint4* srcU = (const uint4*)(UKQ + (size_t)b0*65536);
    uint4* dstU = (uint4*)ukl;
    #pragma unroll
    for (int i=0;i<8;i++) dstU[t + i*1024] = srcU[t + i*1024];
  }
  __syncthreads();
  if (t < 256){
    int bb = t>>7, i = t&127;
    xb[bb][130+i] = pack2(hf[bb][2*i], hf[bb][2*i+1]);
  }
  if (t == 256){
    xb[0][128]=0u; xb[0][129]=0u; xb[0][258]=0u; xb[0][259]=0u;
    xb[1][128]=0u; xb[1][129]=0u; xb[1][258]=0u; xb[1][259]=0u;
  }
  float sumVaH = 0.f;    // sum of Va over e in this thread's S-half
  {
    #pragma unroll 8
    for (int e = eh*128; e < eh*128+128; ++e) sumVaH += va2[e];
    sumVaH *= 0.5f;
  }
  __syncthreads();

  const uint8_t* ukb = ukl + ((size_t)(bi*16 + eh*8)*256 + d)*16;  // S base

  #pragma unroll 1
  for (int step=0; step<NT; ++step){
    // ---- A: fused {q,r,z,n} over h for BOTH batches; quarter q4 -> 32 k2, 2-deep ----
    float a0q=0,a0r=0,a0z=0,a0n=0, a1q=0,a1r=0,a1z=0,a1n=0;
    {
      const uint4* wh = WH + (size_t)(q4*32)*256 + d;
      const uint32_t* xh0 = &xb[0][130 + q4*32];
      const uint32_t* xh1 = &xb[1][130 + q4*32];
      #pragma unroll 1
      for (int kk=0; kk<32; kk+=2){
        uint4 w0 = wh[(size_t)(kk+0)*256];
        uint4 w1 = wh[(size_t)(kk+1)*256];
        uint32_t x00=xh0[kk], x01=xh0[kk+1];
        uint32_t x10=xh1[kk], x11=xh1[kk+1];
        a0q=dot2bf(w0.x,x00,a0q); a0r=dot2bf(w0.y,x00,a0r); a0z=dot2bf(w0.z,x00,a0z); a0n=dot2bf(w0.w,x00,a0n);
        a1q=dot2bf(w0.x,x10,a1q); a1r=dot2bf(w0.y,x10,a1r); a1z=dot2bf(w0.z,x10,a1z); a1n=dot2bf(w0.w,x10,a1n);
        a0q=dot2bf(w1.x,x01,a0q); a0r=dot2bf(w1.y,x01,a0r); a0z=dot2bf(w1.z,x01,a0z); a0n=dot2bf(w1.w,x01,a0n);
        a1q=dot2bf(w1.x,x11,a1q); a1r=dot2bf(w1.y,x11,a1r); a1z=dot2bf(w1.z,x11,a1z); a1n=dot2bf(w1.w,x11,a1n);
      }
    }
    if (q4 < 2){               // stage 1: quarters 0,1 write (row ph = q4)
      scr[ 0+q4][d]=a0q; scr[ 2+q4][d]=a0r; scr[ 4+q4][d]=a0z; scr[ 6+q4][d]=a0n;
      scr[ 8+q4][d]=a1q; scr[10+q4][d]=a1r; scr[12+q4][d]=a1z; scr[14+q4][d]=a1n;
    }
    __syncthreads();
    if (q4 >= 2){              // stage 2: quarters 2,3 accumulate (ph = q4&1)
      const int ph = q4 & 1;
      scr[ 0+ph][d]+=a0q; scr[ 2+ph][d]+=a0r; scr[ 4+ph][d]+=a0z; scr[ 6+ph][d]+=a0n;
      scr[ 8+ph][d]+=a1q; scr[10+ph][d]+=a1r; scr[12+ph][d]+=a1z; scr[14+ph][d]+=a1n;
    }
    __syncthreads();
    if (q4 < 2){               // reduce: batch q4
      const int rb = q4*8;
      qL[q4][d]     = (scr[rb+0][d]+scr[rb+1][d] + ba_d) * C2;
      ghp[q4][0][d] =  scr[rb+2][d]+scr[rb+3][d];
      ghp[q4][1][d] =  scr[rb+4][d]+scr[rb+5][d];
      ghp[q4][2][d] =  scr[rb+6][d]+scr[rb+7][d];
    }
    __syncthreads();

    // ---- S: scores (batch bi, s=d, e-half eh) from LDS fp8, 2-deep ----
    {
      float acc = 0.f;
      #pragma unroll 1
      for (int j=0;j<8;j+=2){
        uint4 u0 = *(const uint4*)(ukb + (size_t)(j+0)*4096);
        uint4 u1 = *(const uint4*)(ukb + (size_t)(j+1)*4096);
        const float* qb = &qL[bi][eh*128 + j*16];
        const float* vb = &va2[eh*128 + j*16];
        acc = s_dword(u0.x, *(const float4*)&qb[0],  *(const float4*)&vb[0],  acc);
        acc = s_dword(u0.y, *(const float4*)&qb[4],  *(const float4*)&vb[4],  acc);
        acc = s_dword(u0.z, *(const float4*)&qb[8],  *(const float4*)&vb[8],  acc);
        acc = s_dword(u0.w, *(const float4*)&qb[12], *(const float4*)&vb[12], acc);
        acc = s_dword(u1.x, *(const float4*)&qb[16], *(const float4*)&vb[16], acc);
        acc = s_dword(u1.y, *(const float4*)&qb[20], *(const float4*)&vb[20], acc);
        acc = s_dword(u1.z, *(const float4*)&qb[24], *(const float4*)&vb[24], acc);
        acc = s_dword(u1.w, *(const float4*)&qb[28], *(const float4*)&vb[28], acc);
      }
      scr[q4][d] = sumVaH - acc;   // rows 0-3: (batch bi, half eh)
    }
    __syncthreads();

    // ---- softmax: q4<2 -> batch q4 ----
    float p_reg = 0.f;
    if (q4 < 2){
      float sc = scr[q4*2+0][d] + scr[q4*2+1][d] + bv0;
      p_reg = exp2_fast(sc * LOG2E);
      float ssum = p_reg;
      #pragma unroll
      for (int o=32;o;o>>=1) ssum += __shfl_xor(ssum, o);
      if (lane==0) red[w] = ssum;   // batch0: red[0..3], batch1: red[4..7]
    }
    __syncthreads();
    if (q4 < 2){
      const int rb = q4*4;
      float ssum = (red[rb]+red[rb+1]) + (red[rb+2]+red[rb+3]);
      float wgt = p_reg * rcp_fast(ssum);
      float* ca_b = ca + (size_t)(b0+q4)*(NT*NS);
      __builtin_nontemporal_store(wgt, &ca_b[(size_t)step*NS + d]);
      wl[q4][d] = wgt;
    }
    __syncthreads();

    // ---- C: ctx via NONTEMPORAL fp8 EP (L3 path; keeps weights in L2) ----
    {
      const int cb = w>>3, sub = w&7;
      const u32x4* epb = (const u32x4*)(EPQ + (size_t)(b0+cb)*16384);
      // epb is indexed in uint4 units: dword index /4
      float c0=0,c1=0,c2=0,c3=0;
      #pragma unroll
      for (int gq=0; gq<2; ++gq){
        const int s40 = sub*8 + gq*4;
        u32x4 e0v = __builtin_nontemporal_load(epb + (size_t)(s40+0)*64 + lane);
        u32x4 e1v = __builtin_nontemporal_load(epb + (size_t)(s40+1)*64 + lane);
        u32x4 e2v = __builtin_nontemporal_load(epb + (size_t)(s40+2)*64 + lane);
        u32x4 e3v = __builtin_nontemporal_load(epb + (size_t)(s40+3)*64 + lane);
        float4 w40 = *(const float4*)&wl[cb][(s40+0)*4];
        c0=c_dword(e0v.x,w40,c0); c1=c_dword(e0v.y,w40,c1);
        c2=c_dword(e0v.z,w40,c2); c3=c_dword(e0v.w,w40,c3);
        float4 w41 = *(const float4*)&wl[cb][(s40+1)*4];
        c0=c_dword(e1v.x,w41,c0); c1=c_dword(e1v.y,w41,c1);
        c2=c_dword(e1v.z,w41,c2); c3=c_dword(e1v.w,w41,c3);
        float4 w42 = *(const float4*)&wl[cb][(s40+2)*4];
        c0=c_dword(e2v.x,w42,c0); c1=c_dword(e2v.y,w42,c1);
        c2=c_dword(e2v.z,w42,c2); c3=c_dword(e2v.w,w42,c3);
        float4 w43 = *(const float4*)&wl[cb][(s40+3)*4];
        c0=c_dword(e3v.x,w43,c0); c1=c_dword(e3v.y,w43,c1);
        c2=c_dword(e3v.z,w43,c2); c3=c_dword(e3v.w,w43,c3);
      }
      *(float4*)&scr[w][lane*4] = make_float4(c0,c1,c2,c3);
    }
    __syncthreads();
    if (q4 < 2){
      float cx = 0.f;
      #pragma unroll
      for (int i=0;i<8;i++) cx += scr[q4*8+i][d];
      float other = __shfl_xor(cx, 1);
      if (!(d&1)) xb[q4][d>>1] = pack2(cx, other);
      if (d==128) xb[q4][128] = pack2(xin[q4][0], xin[q4][1]);
      if (d==129) xb[q4][129] = pack2(xin[q4][2], 0.f);
    }
    __syncthreads();

    // ---- D: x-part gates {r,z,n} for BOTH batches; quarter q4 -> 33 k2, 2-deep ----
    float d0r=0,d0z=0,d0n=0, d1r=0,d1z=0,d1n=0;
    {
      const int k0 = q4*33;
      const uint32_t* wx = WX + ((size_t)k0*256 + d)*3;
      #pragma unroll 1
      for (int kk=0; kk<32; kk+=2){
        const uint32_t* p0 = wx + (size_t)(kk+0)*768;
        const uint32_t* p1 = wx + (size_t)(kk+1)*768;
        uint32_t r0=p0[0], z0=p0[1], n0=p0[2];
        uint32_t r1=p1[0], z1=p1[1], n1=p1[2];
        uint32_t x00=xb[0][k0+kk+0], x01=xb[0][k0+kk+1];
        uint32_t x10=xb[1][k0+kk+0], x11=xb[1][k0+kk+1];
        d0r=dot2bf(r0,x00,d0r); d0z=dot2bf(z0,x00,d0z); d0n=dot2bf(n0,x00,d0n);
        d1r=dot2bf(r0,x10,d1r); d1z=dot2bf(z0,x10,d1z); d1n=dot2bf(n0,x10,d1n);
        d0r=dot2bf(r1,x01,d0r); d0z=dot2bf(z1,x01,d0z); d0n=dot2bf(n1,x01,d0n);
        d1r=dot2bf(r1,x11,d1r); d1z=dot2bf(z1,x11,d1z); d1n=dot2bf(n1,x11,d1n);
      }
      { // 33rd k2
        const uint32_t* p = wx + (size_t)32*768;
        uint32_t xa = xb[0][k0+32], xc = xb[1][k0+32];
        d0r=dot2bf(p[0],xa,d0r); d0z=dot2bf(p[1],xa,d0z); d0n=dot2bf(p[2],xa,d0n);
        d1r=dot2bf(p[0],xc,d1r); d1z=dot2bf(p[1],xc,d1z); d1n=dot2bf(p[2],xc,d1n);
      }
    }
    if (q4 < 2){               // stage 1 write
      scr[ 0+q4][d]=d0r; scr[ 2+q4][d]=d0z; scr[ 4+q4][d]=d0n;
      scr[ 6+q4][d]=d1r; scr[ 8+q4][d]=d1z; scr[10+q4][d]=d1n;
    }
    __syncthreads();
    if (q4 >= 2){              // stage 2 accumulate
      const int ph = q4 & 1;
      scr[ 0+ph][d]+=d0r; scr[ 2+ph][d]+=d0z; scr[ 4+ph][d]+=d0n;
      scr[ 6+ph][d]+=d1r; scr[ 8+ph][d]+=d1z; scr[10+ph][d]+=d1n;
    }
    __syncthreads();
    if (q4 < 2){               // epilogue: batch q4
      const int rb = q4*6;
      float ar  = scr[rb+0][d]+scr[rb+1][d] + ghp[q4][0][d] + bias_r;
      float az  = scr[rb+2][d]+scr[rb+3][d] + ghp[q4][1][d] + bias_z;
      float ani = scr[rb+4][d]+scr[rb+5][d] + bias_ni;
      float anh = ghp[q4][2][d] + bias_nh;
      float rg = sigm_f(ar);
      float zg = sigm_f(az);
      float ng = tanh_f(ani + rg*anh);
      float hnew = (1.f-zg)*ng + zg*hf[q4][d];
      hf[q4][d] = hnew;
      float other = __shfl_xor(hnew, 1);
      if (!(d&1)) xb[q4][130 + (d>>1)] = pack2(hnew, other);
    }
    __syncthreads();

    // ---- out projection: waves 0 (batch0) and 8 (batch1); Wo from L2 ----
    if ((w & 7) == 0){
      const int bq = w >> 3;
      float p0=0,p1=0,p2=0;
      #pragma unroll
      for (int i=0;i<4;i++){
        float hv = hf[bq][i*64 + lane];
        p0 = fmaf(hv, Wo[      i*64+lane], p0);
        p1 = fmaf(hv, Wo[256 + i*64+lane], p1);
        p2 = fmaf(hv, Wo[512 + i*64+lane], p2);
      }
      #pragma unroll
      for (int o=32;o;o>>=1){
        p0+=__shfl_xor(p0,o); p1+=__shfl_xor(p1,o); p2+=__shfl_xor(p2,o);
      }
      if (lane==0){
        float o0=p0+bo0, o1=p1+bo1, o2=p2+bo2;
        float* do_b = dout + (size_t)(b0+bq)*(NT*NO);
        __builtin_nontemporal_store(o0, &do_b[(size_t)step*NO+0]);
        __builtin_nontemporal_store(o1, &do_b[(size_t)step*NO+1]);
        __builtin_nontemporal_store(o2, &do_b[(size_t)step*NO+2]);
        xin[bq][0]=o0; xin[bq][1]=o1; xin[bq][2]=o2;
      }
    }
    // next step's A-phase barriers order xin/hf/xb consumers
  }

  __syncthreads();
  if (q4 < 2) hT_out[(size_t)(b0+q4)*ND + d] = hf[q4][d];
}

// ---------------- host launch ----------------

extern "C" void kernel_launch(void* const* d_in, const int* in_sizes, int n_in,
                              void* d_out, int out_size, void* d_ws, size_t ws_size,
                              hipStream_t stream) {
  const float* e_all  = (const float*)d_in[0];
  const float* e_last = (const float*)d_in[1];
  const float* Wa     = (const float*)d_in[2];
  const float* ba     = (const float*)d_in[3];
  const float* Ua     = (const float*)d_in[4];
  const float* bu     = (const float*)d_in[5];
  const float* Va     = (const float*)d_in[6];
  const float* bv     = (const float*)d_in[7];
  const float* W_ih   = (const float*)d_in[8];
  const float* b_ih   = (const float*)d_in[9];
  const float* W_hh   = (const float*)d_in[10];
  const float* b_hh   = (const float*)d_in[11];
  const float* Wo     = (const float*)d_in[12];
  const float* bo     = (const float*)d_in[13];

  // workspace layout (~68.3 MB)
  char* ws = (char*)d_ws;
  uint8_t*  UKQ = (uint8_t*) (ws + 0ull);            // fp8 [B][16][S][16]    33554432 B
  uint32_t* EPQ = (uint32_t*)(ws + 33554432ull);     // u32 [B][64][256]      33554432 B
  uint4*    WH  = (uint4*)   (ws + 67108864ull);     // u4x [128][256]          524288 B
  uint32_t* WX  = (uint32_t*)(ws + 67633152ull);     // u32 [132][256][3]       405504 B
  float*    UaT = (float*)   (ws + 68038656ull);     // f32 [256][256]          262144 B

  float* dout = (float*)d_out;                       // [B][T][3]
  float* hT   = dout + (size_t)NB*NT*NO;             // [B][D]
  float* ca   = hT   + (size_t)NB*ND;                // [B][T*S]

  // prep
  k_transpose<<<(ND*ND+255)/256,256,0,stream>>>(Ua, UaT, ND, ND);
  k_uk<<<NB*NS/16,256,0,stream>>>(e_all, UaT, bu, UKQ);
  k_epq<<<(NB*64*256+255)/256,256,0,stream>>>(e_all, EPQ);
  k_wh<<<(128*256+255)/256,256,0,stream>>>(Wa, W_hh, WH);
  k_wx<<<(132*256+255)/256,256,0,stream>>>(W_ih, WX);

  // persistent decode: 256 blocks x 1024 threads; 2 batches in lockstep
  k_decode<<<NB/2,1024,0,stream>>>(UKQ, EPQ, WH, WX, e_last, Va, bv,
                                   b_ih, b_hh, ba, bo, Wo, dout, hT, ca);
}

// Round 18
// 6863.440 us; speedup vs baseline: 1.7302x; 1.3598x over previous
//
#include <hip/hip_runtime.h>
#include <hip/hip_bf16.h>
#include <stdint.h>

// Problem sizes (fixed)
#define NB 512     // batch
#define NS 256     // source length
#define ND 256     // hidden dim
#define NT 256     // decode steps
#define NO 3       // output dim

#define LOG2E 1.44269504088896340736f
#define C2 (2.0f*LOG2E)

typedef float f32x2 __attribute__((ext_vector_type(2)));

#if __has_builtin(__builtin_amdgcn_exp2f)
__device__ __forceinline__ float exp2_fast(float x){ return __builtin_amdgcn_exp2f(x); }
#else
__device__ __forceinline__ float exp2_fast(float x){ return exp2f(x); }
#endif
#if __has_builtin(__builtin_amdgcn_rcpf)
__device__ __forceinline__ float rcp_fast(float x){ return __builtin_amdgcn_rcpf(x); }
#else
__device__ __forceinline__ float rcp_fast(float x){ return 1.0f/x; }
#endif

__device__ __forceinline__ float tanh_f(float x){
  float e = exp2_fast(x * C2);
  return 1.0f - 2.0f*rcp_fast(e + 1.0f);
}
__device__ __forceinline__ float sigm_f(float x){
  return rcp_fast(1.0f + exp2_fast(-x*LOG2E));
}
__device__ __forceinline__ float bflo(uint32_t u){ return __uint_as_float(u<<16); }
__device__ __forceinline__ float bfhi(uint32_t u){ return __uint_as_float(u & 0xffff0000u); }
__device__ __forceinline__ uint16_t f2bf(float f){   // round-to-nearest-even bf16
  uint32_t u = __float_as_uint(f);
  return (uint16_t)((u + 0x7fffu + ((u>>16)&1u)) >> 16);
}
__device__ __forceinline__ uint32_t pack2(float a, float b){
  return (uint32_t)f2bf(a) | ((uint32_t)f2bf(b) << 16);
}

// bf16-pair dot product: c + a.lo*b.lo + a.hi*b.hi
#if __has_builtin(__builtin_amdgcn_fdot2_f32_bf16)
typedef __bf16 bfp2 __attribute__((ext_vector_type(2)));
__device__ __forceinline__ float dot2bf(uint32_t a, uint32_t b, float c){
  return __builtin_amdgcn_fdot2_f32_bf16(__builtin_bit_cast(bfp2, a),
                                         __builtin_bit_cast(bfp2, b), c, false);
}
#else
__device__ __forceinline__ float dot2bf(uint32_t a, uint32_t b, float c){
  return c + bflo(a)*bflo(b) + bfhi(a)*bfhi(b);
}
#endif

// ---- fp8 e4m3 (OCP) encode/decode ----
__device__ __forceinline__ uint8_t enc_e4m3(float x){
  uint32_t sign = (__float_as_uint(x) >> 31) << 7;
  float y = fminf(fabsf(x), 448.0f);
  uint32_t u = __float_as_uint(y);
  int e = (int)(u >> 23) - 127;
  uint32_t code;
  if (e < -6){
    code = (uint32_t)__float2int_rn(y * 512.0f);      // denormal (ulp 2^-9)
  } else {
    uint32_t r = u + 0x000FFFFFu + ((u >> 20) & 1u);  // RNE to 3 mantissa bits
    e = (int)(r >> 23) - 127;
    code = (uint32_t)((e + 7) << 3) | ((r >> 20) & 7u);
    if (code > 0x7Eu) code = 0x7Eu;                   // max finite 448
  }
  return (uint8_t)(sign | code);
}

// HI must be a compile-time constant (builtin requires literal immediate).
#if __has_builtin(__builtin_amdgcn_cvt_pk_f32_fp8)
template<bool HI>
__device__ __forceinline__ f32x2 cvtpk_fp8(uint32_t w){
  return __builtin_amdgcn_cvt_pk_f32_fp8((int)w, HI);
}
#else
__device__ __forceinline__ float dec1_e4m3(uint32_t b){
  uint32_t s = (b >> 7) << 31;
  uint32_t em = b & 0x7fu;
  float mag;
  if (em >= 8u){
    mag = __uint_as_float((((em >> 3) + 120u) << 23) | ((em & 7u) << 20));
  } else {
    mag = (float)em * 0.001953125f;  // 2^-9
  }
  return __uint_as_float(s | __float_as_uint(mag));
}
template<bool HI>
__device__ __forceinline__ f32x2 cvtpk_fp8(uint32_t w){
  uint32_t p = HI ? (w >> 16) : (w & 0xffffu);
  f32x2 r; r.x = dec1_e4m3(p & 0xffu); r.y = dec1_e4m3(p >> 8); return r;
}
#endif

// S-phase: one dword = 4 consecutive e's. Temps die immediately (low VGPR).
__device__ __forceinline__ float s_dword(uint32_t dwv, float4 qq, float4 vv, float acc){
  f32x2 lo = cvtpk_fp8<false>(dwv);
  f32x2 hi = cvtpk_fp8<true>(dwv);
  float r;
  r = rcp_fast(exp2_fast(lo.x + qq.x) + 1.f); acc = fmaf(vv.x, r, acc);
  r = rcp_fast(exp2_fast(lo.y + qq.y) + 1.f); acc = fmaf(vv.y, r, acc);
  r = rcp_fast(exp2_fast(hi.x + qq.z) + 1.f); acc = fmaf(vv.z, r, acc);
  r = rcp_fast(exp2_fast(hi.y + qq.w) + 1.f); acc = fmaf(vv.w, r, acc);
  return acc;
}
// C-phase: one dword = 4 s-values of one dim, weighted by w4.
__device__ __forceinline__ float c_dword(uint32_t dwv, float4 w4, float acc){
  f32x2 lo = cvtpk_fp8<false>(dwv);
  f32x2 hi = cvtpk_fp8<true>(dwv);
  return fmaf(w4.x,lo.x, fmaf(w4.y,lo.y, fmaf(w4.z,hi.x, fmaf(w4.w,hi.y, acc))));
}

// ---------------- prep kernels ----------------

__global__ void k_transpose(const float* __restrict__ src, float* __restrict__ dst,
                            int R, int C){
  int idx = blockIdx.x*256 + threadIdx.x;
  if (idx < R*C){
    int r = idx / C, c = idx - r*C;
    dst[c*R + r] = src[idx];
  }
}

// UKQ[b][e16][s][16] fp8 e4m3, PRE-SCALED by 2*log2e: byte j of group = e (e16*16+j)
__global__ void __launch_bounds__(256) k_uk(const float* __restrict__ e_all,
    const float* __restrict__ UaT, const float* __restrict__ bu,
    uint8_t* __restrict__ UKQ){
  __shared__ float At[ND][20];
  const int t = threadIdx.x;
  const int m0 = blockIdx.x * 16;
  const int b  = m0 >> 8;
  const int s0 = m0 & (NS-1);
  #pragma unroll
  for (int i=0;i<16;i++)
    At[t][i] = e_all[(size_t)(m0+i)*ND + t];
  __syncthreads();
  float acc[16];
  float bue = bu[t];
  #pragma unroll
  for (int i=0;i<16;i++) acc[i] = bue;
  for (int d=0; d<ND; ++d){
    float u = UaT[d*ND + t];
    const float4 a0 = *(const float4*)&At[d][0];
    const float4 a1 = *(const float4*)&At[d][4];
    const float4 a2 = *(const float4*)&At[d][8];
    const float4 a3 = *(const float4*)&At[d][12];
    acc[0]+=a0.x*u;  acc[1]+=a0.y*u;  acc[2]+=a0.z*u;  acc[3]+=a0.w*u;
    acc[4]+=a1.x*u;  acc[5]+=a1.y*u;  acc[6]+=a1.z*u;  acc[7]+=a1.w*u;
    acc[8]+=a2.x*u;  acc[9]+=a2.y*u;  acc[10]+=a2.z*u; acc[11]+=a2.w*u;
    acc[12]+=a3.x*u; acc[13]+=a3.y*u; acc[14]+=a3.z*u; acc[15]+=a3.w*u;
  }
  const int e16 = t>>4, j = t&15;
  uint8_t* base = UKQ + (((size_t)b*16 + e16)*256 + s0)*16 + j;
  #pragma unroll
  for (int i=0;i<16;i++){
    uint32_t mine = enc_e4m3(acc[i] * C2);
    uint32_t other = (uint32_t)__shfl_xor((int)mine, 1);
    if (!(t & 1))
      *(uint16_t*)(base + (size_t)i*16) = (uint16_t)(mine | (other << 8));
  }
}

// EPQ[b][s4][d] u32 = fp8 {e[4s4+0][d], e[4s4+1][d], e[4s4+2][d], e[4s4+3][d]}
__global__ void k_epq(const float* __restrict__ e_all, uint32_t* __restrict__ EPQ){
  int idx = blockIdx.x*256 + threadIdx.x;
  if (idx >= NB*64*256) return;
  int d  = idx & 255;
  int s4 = (idx >> 8) & 63;
  int b  = idx >> 14;
  const float* e = e_all + ((size_t)b*NS + 4*s4)*ND + d;
  uint32_t v = (uint32_t)enc_e4m3(e[0])
             | ((uint32_t)enc_e4m3(e[ND])   << 8)
             | ((uint32_t)enc_e4m3(e[2*ND]) << 16)
             | ((uint32_t)enc_e4m3(e[3*ND]) << 24);
  EPQ[idx] = v;
}

// PKq[k2][g][d] u32 pairs over combined K-axis:
//   k2 in [0,130): x-part pairs {k=2k2, 2k2+1} of W_ih (k<259, else 0)
//   k2 in [130,258): h-part pairs of W_hh ; [258,260): zero pad
__global__ void k_pkq(const float* __restrict__ W_ih, const float* __restrict__ W_hh,
                      uint32_t* __restrict__ PKq){
  int idx = blockIdx.x*256 + threadIdx.x;   // ((k2*3)+g)*256 + d
  if (idx >= 260*3*256) return;
  int d  = idx & 255;
  int gk = idx >> 8;
  int k2 = gk/3, g = gk - 3*k2;
  int col = g*256 + d;
  float w0 = 0.f, w1 = 0.f;
  if (k2 < 130){
    int k0 = 2*k2, k1 = k0+1;
    w0 = W_ih[(size_t)col*259 + k0];
    w1 = (k1 < 259) ? W_ih[(size_t)col*259 + k1] : 0.f;
  } else if (k2 < 258){
    int kk = 2*(k2-130);
    w0 = W_hh[(size_t)col*256 + kk];
    w1 = W_hh[(size_t)col*256 + kk+1];
  }
  PKq[idx] = pack2(w0, w1);
}

// PQ[k2][d] = {bf16 Wa[d][2k2], bf16 Wa[d][2k2+1]}
__global__ void k_pack_q(const float* __restrict__ Wa, uint32_t* __restrict__ PQ){
  int idx = blockIdx.x*256 + threadIdx.x;   // k2*256 + d
  if (idx >= 128*256) return;
  int d = idx & 255, k2 = idx >> 8;
  PQ[idx] = pack2(Wa[(size_t)d*256 + 2*k2], Wa[(size_t)d*256 + 2*k2 + 1]);
}

// ---------------- persistent decode kernel ----------------
// 256 blocks x 1024 threads; each block processes its TWO batches SEQUENTIALLY
// (2 rounds x 256 steps). Per round, that batch's fp8 UK (64KB) + EP (64KB)
// live in LDS -> steady-state global traffic = L2-resident weights only.
// t: d = t&255, q4 = t>>8 (quarter), lane = t&63, w = t>>6 (0..15).
__global__ void __launch_bounds__(1024, 4) k_decode(
    const uint8_t* __restrict__ UKQ, const uint32_t* __restrict__ EPQ,
    const uint32_t* __restrict__ PKq, const uint32_t* __restrict__ PQ,
    const float* __restrict__ e_last,
    const float* __restrict__ Va, const float* __restrict__ bv,
    const float* __restrict__ b_ih, const float* __restrict__ b_hh,
    const float* __restrict__ ba, const float* __restrict__ bo,
    const float* __restrict__ Wo,
    float* __restrict__ dout, float* __restrict__ hT_out, float* __restrict__ ca)
{
  __shared__ __align__(16) uint8_t  ukl[65536];   // fp8 UK, this round's batch
  __shared__ __align__(16) uint32_t epl[16384];   // fp8 EP (dwords)
  __shared__ __align__(16) float    scr[16][ND];  // union: qpart/spart(4) | cpart(16) | gpart(12)
  __shared__ float    hf[ND];
  __shared__ float    xin[4];
  __shared__ uint32_t xb[260];                    // bf16 pairs: [0..129]=ctx+x, [130..257]=h, pad
  __shared__ __align__(16) float qL[ND];
  __shared__ __align__(16) float va2[ND];         // 2*Va
  __shared__ float    WoL[3*ND];
  __shared__ __align__(16) float wl[NS];          // softmax weights (f32)
  __shared__ float    red[8];

  const int t    = threadIdx.x;
  const int d    = t & 255;
  const int q4   = t >> 8;
  const int lane = t & 63;
  const int w    = t >> 6;
  const int b0   = blockIdx.x * 2;

  // ---- one-time init ----
  if (q4 == 0){
    va2[d] = 2.0f*Va[d];
    WoL[d] = Wo[d]; WoL[256+d] = Wo[256+d]; WoL[512+d] = Wo[512+d];
  }
  const float bias_r  = b_ih[d]     + b_hh[d];
  const float bias_z  = b_ih[256+d] + b_hh[256+d];
  const float bias_ni = b_ih[512+d];
  const float bias_nh = b_hh[512+d];
  const float ba_d = ba[d];
  const float bv0  = bv[0];
  const float bo0 = bo[0], bo1 = bo[1], bo2 = bo[2];
  __syncthreads();
  float sumVaQ = 0.f;      // sum of Va over e in [q4*64, q4*64+64)
  {
    #pragma unroll 8
    for (int e = q4*64; e < q4*64+64; ++e) sumVaQ += va2[e];
    sumVaQ *= 0.5f;
  }

  #pragma unroll 1
  for (int r=0; r<2; ++r){
    const int b = b0 + r;

    // ---- per-round init: LDS data load + state reset ----
    {
      const uint4* srcU = (const uint4*)(UKQ + (size_t)b*65536);
      uint4* dstU = (uint4*)ukl;
      #pragma unroll
      for (int i=0;i<4;i++) dstU[t + i*1024] = srcU[t + i*1024];
      const uint4* srcE = (const uint4*)(EPQ + (size_t)b*16384);
      uint4* dstE = (uint4*)epl;
      #pragma unroll
      for (int i=0;i<4;i++) dstE[t + i*1024] = srcE[t + i*1024];
    }
    if (q4 == 0){
      hf[d] = e_last[(size_t)b*ND + d];
      if (d < 4) xin[d] = 0.f;
    }
    __syncthreads();
    if (t < 128) xb[130+t] = pack2(hf[2*t], hf[2*t+1]);
    if (t == 128){ xb[128]=0u; xb[129]=0u; xb[258]=0u; xb[259]=0u; }
    __syncthreads();

    float* ca_b = ca   + (size_t)b*(NT*NS);
    float* do_b = dout + (size_t)b*(NT*NO);

    #pragma unroll 1
    for (int step=0; step<NT; ++step){
      // ---- Q: q = h @ Wa^T + ba ; quarter q4 of k2 (32 each) ----
      {
        float aq = 0.f;
        const uint32_t* pq = PQ + (size_t)(q4*32)*256 + d;
        const uint32_t* xh = &xb[130 + q4*32];
        #pragma unroll 1
        for (int kk=0; kk<32; kk+=8){
          uint32_t wv[8], xv[8];
          #pragma unroll
          for (int j=0;j<8;j++){ wv[j] = pq[(kk+j)*256]; xv[j] = xh[kk+j]; }
          #pragma unroll
          for (int j=0;j<8;j++) aq = dot2bf(wv[j], xv[j], aq);
        }
        scr[q4][d] = aq;
      }
      __syncthreads();
      if (q4 == 0)
        qL[d] = ((scr[0][d]+scr[1][d]) + (scr[2][d]+scr[3][d]) + ba_d) * C2;
      __syncthreads();

      // ---- S: scores (s=d, e-quarter q4) from LDS fp8 ; folded tanh ----
      {
        float acc = 0.f;
        #pragma unroll
        for (int j=0;j<4;j++){
          uint4 u = *(const uint4*)(ukl + (size_t)(q4*4+j)*4096 + d*16);
          const float* qb = &qL[q4*64 + j*16];
          const float* vb = &va2[q4*64 + j*16];
          acc = s_dword(u.x, *(const float4*)&qb[0],  *(const float4*)&vb[0],  acc);
          acc = s_dword(u.y, *(const float4*)&qb[4],  *(const float4*)&vb[4],  acc);
          acc = s_dword(u.z, *(const float4*)&qb[8],  *(const float4*)&vb[8],  acc);
          acc = s_dword(u.w, *(const float4*)&qb[12], *(const float4*)&vb[12], acc);
        }
        scr[q4][d] = sumVaQ - acc;   // qpart dead; reuse rows 0-3
      }
      __syncthreads();

      // ---- softmax (no max-subtract; |score| <= sum|Va|+|bv| is small) ----
      float p_reg = 0.f;
      if (q4 == 0){
        float sc = (scr[0][d]+scr[1][d]) + (scr[2][d]+scr[3][d]) + bv0;
        p_reg = exp2_fast(sc * LOG2E);
        float ssum = p_reg;
        #pragma unroll
        for (int o=32;o;o>>=1) ssum += __shfl_xor(ssum, o);
        if (lane==0) red[w] = ssum;      // waves 0-3
      }
      __syncthreads();
      if (q4 == 0){
        float ssum = (red[0]+red[1]) + (red[2]+red[3]);
        float wgt = p_reg * rcp_fast(ssum);
        __builtin_nontemporal_store(wgt, &ca_b[(size_t)step*NS + d]);
        wl[d] = wgt;
      }
      __syncthreads();

      // ---- C: ctx from LDS fp8 ; wave w -> s4 in [w*4, w*4+4) ----
      {
        float c0=0,c1=0,c2=0,c3=0;
        #pragma unroll
        for (int i=0;i<4;i++){
          int s4 = w*4 + i;
          uint4 ev = *(const uint4*)(epl + (size_t)s4*256 + lane*4);
          float4 w4 = *(const float4*)&wl[s4*4];
          c0 = c_dword(ev.x, w4, c0);
          c1 = c_dword(ev.y, w4, c1);
          c2 = c_dword(ev.z, w4, c2);
          c3 = c_dword(ev.w, w4, c3);
        }
        *(float4*)&scr[w][lane*4] = make_float4(c0,c1,c2,c3);
      }
      __syncthreads();
      if (q4 == 0){
        float cx = 0.f;
        #pragma unroll
        for (int i=0;i<16;i++) cx += scr[i][d];
        float other = __shfl_xor(cx, 1);
        if (!(d&1)) xb[d>>1] = pack2(cx, other);
        if (d==128) xb[128] = pack2(xin[0], xin[1]);
        if (d==129) xb[129] = pack2(xin[2], 0.f);
      }
      __syncthreads();

      // ---- G: gates ; quarter q4 of k2 (65 each: 0,1=x-part; 2,3=h-part) ----
      {
        float ar=0.f, az=0.f, an=0.f;
        const int k0 = q4*65;
        const uint32_t* pk = PKq + (size_t)k0*768 + d;
        #pragma unroll 1
        for (int g=0; g<64; g+=8){
          uint32_t wr[8], wz[8], wn[8], xv[8];
          #pragma unroll
          for (int j=0;j<8;j++){
            const uint32_t* p = pk + (size_t)(g+j)*768;
            wr[j]=p[0]; wz[j]=p[256]; wn[j]=p[512];
            xv[j]=xb[k0+g+j];
          }
          #pragma unroll
          for (int j=0;j<8;j++){
            ar=dot2bf(wr[j],xv[j],ar); az=dot2bf(wz[j],xv[j],az); an=dot2bf(wn[j],xv[j],an);
          }
        }
        { // 65th k2
          const uint32_t* p = pk + (size_t)64*768;
          uint32_t xa = xb[k0+64];
          ar=dot2bf(p[0],xa,ar); az=dot2bf(p[256],xa,az); an=dot2bf(p[512],xa,an);
        }
        scr[q4*3+0][d]=ar; scr[q4*3+1][d]=az; scr[q4*3+2][d]=an;
      }
      __syncthreads();
      if (q4 == 0){
        float ar  = (scr[0][d]+scr[3][d]) + (scr[6][d]+scr[9][d]) + bias_r;
        float az  = (scr[1][d]+scr[4][d]) + (scr[7][d]+scr[10][d]) + bias_z;
        float ani =  scr[2][d]+scr[5][d]  + bias_ni;   // x-part (k2<130)
        float anh =  scr[8][d]+scr[11][d] + bias_nh;   // h-part
        float rg = sigm_f(ar);
        float zg = sigm_f(az);
        float ng = tanh_f(ani + rg*anh);
        float hnew = (1.f-zg)*ng + zg*hf[d];
        hf[d] = hnew;
        float other = __shfl_xor(hnew, 1);
        if (!(d&1)) xb[130 + (d>>1)] = pack2(hnew, other);
      }
      __syncthreads();

      // ---- out projection: wave 0 ----
      if (w == 0){
        float p0=0,p1=0,p2=0;
        #pragma unroll
        for (int i=0;i<4;i++){
          float hv = hf[i*64 + lane];
          p0 = fmaf(hv, WoL[      i*64+lane], p0);
          p1 = fmaf(hv, WoL[256 + i*64+lane], p1);
          p2 = fmaf(hv, WoL[512 + i*64+lane], p2);
        }
        #pragma unroll
        for (int o=32;o;o>>=1){
          p0+=__shfl_xor(p0,o); p1+=__shfl_xor(p1,o); p2+=__shfl_xor(p2,o);
        }
        if (lane==0){
          float o0=p0+bo0, o1=p1+bo1, o2=p2+bo2;
          __builtin_nontemporal_store(o0, &do_b[(size_t)step*NO+0]);
          __builtin_nontemporal_store(o1, &do_b[(size_t)step*NO+1]);
          __builtin_nontemporal_store(o2, &do_b[(size_t)step*NO+2]);
          xin[0]=o0; xin[1]=o1; xin[2]=o2;
        }
      }
      // next step's barriers order xin/hf consumers
    }

    __syncthreads();
    if (q4 == 0) hT_out[(size_t)b*ND + d] = hf[d];
    __syncthreads();   // before next round overwrites LDS
  }
}

// ---------------- host launch ----------------

extern "C" void kernel_launch(void* const* d_in, const int* in_sizes, int n_in,
                              void* d_out, int out_size, void* d_ws, size_t ws_size,
                              hipStream_t stream) {
  const float* e_all  = (const float*)d_in[0];
  const float* e_last = (const float*)d_in[1];
  const float* Wa     = (const float*)d_in[2];
  const float* ba     = (const float*)d_in[3];
  const float* Ua     = (const float*)d_in[4];
  const float* bu     = (const float*)d_in[5];
  const float* Va     = (const float*)d_in[6];
  const float* bv     = (const float*)d_in[7];
  const float* W_ih   = (const float*)d_in[8];
  const float* b_ih   = (const float*)d_in[9];
  const float* W_hh   = (const float*)d_in[10];
  const float* b_hh   = (const float*)d_in[11];
  const float* Wo     = (const float*)d_in[12];
  const float* bo     = (const float*)d_in[13];

  // workspace layout (~68.3 MB)
  char* ws = (char*)d_ws;
  uint8_t*  UKQ = (uint8_t*) (ws + 0ull);            // fp8 [B][16][S][16]    33554432 B
  uint32_t* EPQ = (uint32_t*)(ws + 33554432ull);     // u32 [B][64][256]      33554432 B
  uint32_t* PKq = (uint32_t*)(ws + 67108864ull);     // u32 [260][3][256]       798720 B
  uint32_t* PQ  = (uint32_t*)(ws + 67907584ull);     // u32 [128][256]          131072 B
  float*    UaT = (float*)   (ws + 68038656ull);     // f32 [256][256]          262144 B

  float* dout = (float*)d_out;                       // [B][T][3]
  float* hT   = dout + (size_t)NB*NT*NO;             // [B][D]
  float* ca   = hT   + (size_t)NB*ND;                // [B][T*S]

  // prep
  k_transpose<<<(ND*ND+255)/256,256,0,stream>>>(Ua, UaT, ND, ND);
  k_uk<<<NB*NS/16,256,0,stream>>>(e_all, UaT, bu, UKQ);
  k_epq<<<(NB*64*256+255)/256,256,0,stream>>>(e_all, EPQ);
  k_pkq<<<(260*3*256+255)/256,256,0,stream>>>(W_ih, W_hh, PKq);
  k_pack_q<<<(128*256+255)/256,256,0,stream>>>(Wa, PQ);

  // persistent decode: 256 blocks x 1024 threads; 2 sequential rounds/block
  k_decode<<<NB/2,1024,0,stream>>>(UKQ, EPQ, PKq, PQ, e_last, Va, bv,
                                   b_ih, b_hh, ba, bo, Wo, dout, hT, ca);
}